// Round 10
// baseline (347.377 us; speedup 1.0000x reference)
//
#include <hip/hip_runtime.h>
#include <hip/hip_bf16.h>

#define T_TOK 1024
#define HDIM  1024
#define NEXP  64
#define IDIM  512
#define SIDIM 1024
#define NGRP  8
#define GSZ   8
#define TKGN  3
#define TOPKN 6
#define CAPS  14336

typedef __attribute__((ext_vector_type(8))) short bf16x8;
typedef __attribute__((ext_vector_type(4))) float f32x4;

__device__ __forceinline__ short f2bf(float f) {
  union { __hip_bfloat16 h; short s; } u;
  u.h = __float2bfloat16(f);
  return u.s;
}
__device__ __forceinline__ float bf2f(short s) {
  union { float f; unsigned u; } c;
  c.u = ((unsigned)(unsigned short)s) << 16;
  return c.f;
}

// global->LDS direct copy, 16B per lane. LDS dest = wave-uniform base + lane*16.
__device__ __forceinline__ void gld16(const void* g, void* l) {
  typedef __attribute__((address_space(1))) const unsigned int GU;
  typedef __attribute__((address_space(3))) unsigned int LU;
  __builtin_amdgcn_global_load_lds((GU*)g, (LU*)l, 16, 0, 0);
}

// counted-vmcnt barrier: stage s+1 retired, stage s+2 (4 loads) stays in flight
#define WAIT4_BAR() asm volatile("s_waitcnt vmcnt(4) lgkmcnt(0)\n\ts_barrier" ::: "memory")
#define WAIT0_BAR() asm volatile("s_waitcnt vmcnt(0) lgkmcnt(0)\n\ts_barrier" ::: "memory")

// ---------------- K0: zero counters ----------------
__global__ void k0_init(int* counts, int* cursor) {
  int i = threadIdx.x;
  if (i < NEXP) { counts[i] = 0; cursor[i] = 0; }
}

// ---- pipelined transpose job: nt tiles (64x64) down the row dim of one panel
// (cy, m). Block writes FULL output rows (write locality) and overlaps tile
// i+1 global loads under tile i's LDS/store phase (latency hiding).
__device__ __forceinline__ void trans_job(
    const float* __restrict__ src, __hip_bfloat16* __restrict__ dst,
    int R, int C, int m, int cy, int nt, short* t /*64*66 LDS shorts*/) {
  int tid = threadIdx.x;
  int r = tid >> 2, c16 = (tid & 3) * 16;
  const float* sbase = src + (size_t)m * R * C + (size_t)r * C + cy * 64 + c16;
  short* dbase = (short*)dst + (size_t)m * R * C + (size_t)(cy * 64) * R;

  float4 v0, v1, v2, v3;
  auto LOADT = [&](int i) {
    const float* p = sbase + (size_t)i * 64 * C;
    v0 = *(const float4*)p;       v1 = *(const float4*)(p + 4);
    v2 = *(const float4*)(p + 8); v3 = *(const float4*)(p + 12);
  };

  LOADT(0);
  for (int i = 0; i < nt; ++i) {
    // convert current regs first (frees v for the next prefetch)
    bf16x8 w0, w1;
    w0[0] = f2bf(v0.x); w0[1] = f2bf(v0.y); w0[2] = f2bf(v0.z); w0[3] = f2bf(v0.w);
    w0[4] = f2bf(v1.x); w0[5] = f2bf(v1.y); w0[6] = f2bf(v1.z); w0[7] = f2bf(v1.w);
    w1[0] = f2bf(v2.x); w1[1] = f2bf(v2.y); w1[2] = f2bf(v2.z); w1[3] = f2bf(v2.w);
    w1[4] = f2bf(v3.x); w1[5] = f2bf(v3.y); w1[6] = f2bf(v3.z); w1[7] = f2bf(v3.w);
    if (i + 1 < nt) LOADT(i + 1);     // in flight across both barriers + stores
    __syncthreads();                   // prior tile's read phase done
    *(bf16x8*)&t[r * 66 + c16] = w0;
    *(bf16x8*)&t[r * 66 + c16 + 8] = w1;
    __syncthreads();                   // tile ready
    #pragma unroll
    for (int p = 0; p < 2; ++p) {
      int oc = (tid >> 3) + p * 32;
      int r0 = (tid & 7) * 8;
      bf16x8 o;
      #pragma unroll
      for (int j = 0; j < 8; ++j) o[j] = t[(r0 + j) * 66 + oc];
      *(bf16x8*)(dbase + (size_t)oc * R + i * 64 + r0) = o;
    }
  }
}

// ---------------- prep1: wg_t | wu_t | swg_t | swu_t | x->bf16 --------------
// jobs: [0,512) wg (m=j>>3, cy=j&7, nt=16) ; [512,1024) wu ;
//       [1024,1040) swg ; [1040,1056) swu ; [1056,1120) xconv (16 rows each)
__global__ __launch_bounds__(256) void prep1(
    const float* __restrict__ wgate, const float* __restrict__ wup,
    const float* __restrict__ swg, const float* __restrict__ swu,
    const float* __restrict__ x,
    __hip_bfloat16* __restrict__ wt_g, __hip_bfloat16* __restrict__ wt_u,
    __hip_bfloat16* __restrict__ ts_g, __hip_bfloat16* __restrict__ ts_u,
    __hip_bfloat16* __restrict__ xb) {
  __shared__ short t[64 * 66];
  int j = blockIdx.x;
  if (j < 512) {
    trans_job(wgate, wt_g, HDIM, IDIM, j >> 3, j & 7, 16, t);
  } else if (j < 1024) {
    int b = j - 512;
    trans_job(wup, wt_u, HDIM, IDIM, b >> 3, b & 7, 16, t);
  } else if (j < 1040) {
    trans_job(swg, ts_g, HDIM, SIDIM, 0, j - 1024, 16, t);
  } else if (j < 1056) {
    trans_job(swu, ts_u, HDIM, SIDIM, 0, j - 1040, 16, t);
  } else {
    int b = j - 1056;                  // 64 jobs, 16 rows each
    int tid = threadIdx.x;
    #pragma unroll
    for (int it = 0; it < 8; ++it) {
      int row = b * 16 + it * 2 + (tid >> 7);
      int c = (tid & 127) * 8;
      const float* s = x + (size_t)row * HDIM + c;
      float4 a0 = *(const float4*)s;
      float4 a1 = *(const float4*)(s + 4);
      bf16x8 o;
      o[0] = f2bf(a0.x); o[1] = f2bf(a0.y); o[2] = f2bf(a0.z); o[3] = f2bf(a0.w);
      o[4] = f2bf(a1.x); o[5] = f2bf(a1.y); o[6] = f2bf(a1.z); o[7] = f2bf(a1.w);
      *(bf16x8*)((short*)xb + (size_t)row * HDIM + c) = o;
    }
  }
}

// ---------------- prep2: wd_t | swd_t ----------------
// jobs: [0,1024) wd (m=j>>4, cy=j&15, nt=8) ; [1024,1040) swd (nt=16)
__global__ __launch_bounds__(256) void prep2(
    const float* __restrict__ wdown, const float* __restrict__ swd,
    __hip_bfloat16* __restrict__ wt_d, __hip_bfloat16* __restrict__ ts_d) {
  __shared__ short t[64 * 66];
  int j = blockIdx.x;
  if (j < 1024) {
    trans_job(wdown, wt_d, IDIM, HDIM, j >> 4, j & 15, 8, t);
  } else {
    trans_job(swd, ts_d, SIDIM, HDIM, 0, j - 1024, 16, t);
  }
}

// ---------------- K1: gating + grouped top-k (1 token / block) --------------
__global__ __launch_bounds__(256) void k1_gate(
    const float* __restrict__ x, const float* __restrict__ gw,
    const float* __restrict__ ebias,
    int* __restrict__ ids, float* __restrict__ wts, int* __restrict__ counts) {
  int t = blockIdx.x;
  int tid = threadIdx.x;
  int lane = tid & 63;   // expert
  int sub = tid >> 6;    // h-chunk
  __shared__ float sx[HDIM];
  __shared__ double spart[4][NEXP];
  __shared__ float s_sc[NEXP], s_sig[NEXP];
  *(float4*)&sx[tid * 4] = *(const float4*)(x + (size_t)t * HDIM + tid * 4);
  __syncthreads();
  const float* gwp = gw + lane;
  int h0 = sub * 256;
  double a0 = 0.0, a1 = 0.0, a2 = 0.0, a3 = 0.0;
  for (int h = h0; h < h0 + 256; h += 4) {
    a0 += (double)sx[h + 0] * (double)gwp[(size_t)(h + 0) * NEXP];
    a1 += (double)sx[h + 1] * (double)gwp[(size_t)(h + 1) * NEXP];
    a2 += (double)sx[h + 2] * (double)gwp[(size_t)(h + 2) * NEXP];
    a3 += (double)sx[h + 3] * (double)gwp[(size_t)(h + 3) * NEXP];
  }
  spart[sub][lane] = (a0 + a1) + (a2 + a3);
  __syncthreads();
  if (tid < NEXP) {
    float logit = (float)(((spart[0][tid] + spart[1][tid]) +
                           (spart[2][tid] + spart[3][tid])));
    float sig = 1.f / (1.f + expf(-logit));
    s_sig[tid] = sig;
    s_sc[tid] = sig + ebias[tid];
  }
  __syncthreads();
  if (tid == 0) {
    const float* ssc = s_sc;
    const float* ssig = s_sig;
    float gsum[NGRP];
    for (int g = 0; g < NGRP; ++g) {
      float m1 = -1e30f; int i1 = -1;
      for (int i = 0; i < GSZ; ++i) {
        float v = ssc[g * GSZ + i];
        if (v > m1) { m1 = v; i1 = i; }
      }
      float m2 = -1e30f;
      for (int i = 0; i < GSZ; ++i) {
        if (i == i1) continue;
        float v = ssc[g * GSZ + i];
        if (v > m2) m2 = v;
      }
      gsum[g] = m1 + m2;
    }
    unsigned gselmask = 0;
    for (int r = 0; r < TKGN; ++r) {
      float best = -1e30f; int bi = 0;
      for (int g = 0; g < NGRP; ++g) {
        if ((gselmask >> g) & 1) continue;
        if (gsum[g] > best) { best = gsum[g]; bi = g; }
      }
      gselmask |= 1u << bi;
    }
    unsigned long long taken = 0;
    int chosen[TOPKN]; float wsum = 0.f;
    for (int r = 0; r < TOPKN; ++r) {
      float best = -1e30f; int bi = 0;
      for (int e = 0; e < NEXP; ++e) {
        if (!((gselmask >> (e >> 3)) & 1)) continue;
        if ((taken >> e) & 1) continue;
        float v = ssc[e];
        if (v > best) { best = v; bi = e; }
      }
      taken |= 1ull << bi;
      chosen[r] = bi;
      wsum += ssig[bi];
    }
    for (int r = 0; r < TOPKN; ++r) {
      ids[t * TOPKN + r] = chosen[r];
      wts[t * TOPKN + r] = ssig[chosen[r]] / wsum;
      atomicAdd(&counts[chosen[r]], 1);
    }
  }
}

// ---------------- K1b: offsets + worklist + slot init ----------------
__global__ void k1b_scan(const int* __restrict__ counts, int* __restrict__ eoff,
                         int* __restrict__ tile_e, int* __restrict__ tile_base,
                         int* __restrict__ nt_p, int* __restrict__ slot_tok) {
  __shared__ int soff[NEXP + 1];
  __shared__ int s_total;
  int tid = threadIdx.x;
  if (tid == 0) {
    int o = 0, idx = 0;
    for (int e = 0; e < NEXP; ++e) {
      soff[e] = o;
      int ntile = (counts[e] + 127) >> 7;
      for (int t2 = 0; t2 < ntile; ++t2) { tile_e[idx] = e; tile_base[idx] = o + t2 * 128; ++idx; }
      o += ntile << 7;
    }
    soff[NEXP] = o; nt_p[0] = idx; s_total = o;
  }
  __syncthreads();
  if (tid <= NEXP) eoff[tid] = soff[tid];
  int total = s_total;
  for (int i = tid; i < total; i += blockDim.x) slot_tok[i] = 0;
}

// ---------------- K1c: fill compact slots + token->slot map ----------------
__global__ void k1c_fill(const int* __restrict__ ids,
                         const int* __restrict__ eoff, int* __restrict__ cursor,
                         int* __restrict__ slot_tok, int* __restrict__ tslot) {
  int i = blockIdx.x * blockDim.x + threadIdx.x;
  if (i >= T_TOK * TOPKN) return;
  int e = ids[i];
  int s = eoff[e] + atomicAdd(&cursor[e], 1);
  slot_tok[s] = i / TOPKN;
  tslot[i] = s;
}

// ------- K2 tile: mid = silu(A@Wg^T)*(A@Wu^T); 128m x 64n, 3-buf vmcnt(4) ---
__device__ __forceinline__ void tile_mid2(
    const __hip_bfloat16* __restrict__ xb,
    const __hip_bfloat16* __restrict__ wtg, const __hip_bfloat16* __restrict__ wtu,
    const int* __restrict__ slot_tok, int rowbase, int ic0, int IC,
    __hip_bfloat16* __restrict__ mid,
    short* As, short* Bg, short* Bu) {
  int tid = threadIdx.x;
  int wave = tid >> 6, lane = tid & 63;
  int wm = wave >> 1, wn = wave & 1;
  int lr = lane & 15, lk = lane >> 4;

  int rh = lane >> 3;
  int lh = ((lane & 7) ^ rh) * 8;
  int r0 = rowbase + wave * 16 + rh;
  int t0 = slot_tok ? slot_tok[r0] : r0;
  int t1 = slot_tok ? slot_tok[r0 + 8] : (r0 + 8);
  const short* ga0 = (const short*)xb + (size_t)t0 * HDIM + lh;
  const short* ga1 = (const short*)xb + (size_t)t1 * HDIM + lh;
  const short* gbg = (const short*)wtg + (size_t)(ic0 + wave * 8 + rh) * HDIM + lh;
  const short* gbu = (const short*)wtu + (size_t)(ic0 + wave * 8 + rh) * HDIM + lh;

  f32x4 accg[2][2], accu[2][2];
  #pragma unroll
  for (int a = 0; a < 2; ++a)
    #pragma unroll
    for (int b = 0; b < 2; ++b) { accg[a][b] = (f32x4)0.f; accu[a][b] = (f32x4)0.f; }

  auto STAGE = [&](int buf, int s) {
    char* ab = (char*)As + buf * 16384 + wave * 2048;
    gld16(ga0 + s * 64, ab);
    gld16(ga1 + s * 64, ab + 1024);
    gld16(gbg + s * 64, (char*)Bg + buf * 8192 + wave * 1024);
    gld16(gbu + s * 64, (char*)Bu + buf * 8192 + wave * 1024);
  };
  auto COMPUTE = [&](int buf) {
    const short* as = As + buf * 8192;
    const short* bg = Bg + buf * 4096;
    const short* bu = Bu + buf * 4096;
    #pragma unroll
    for (int kk = 0; kk < 2; ++kk) {
      bf16x8 af[2];
      #pragma unroll
      for (int mf = 0; mf < 2; ++mf) {
        int row = wm * 32 + mf * 16 + lr;
        af[mf] = *(const bf16x8*)&as[row * 64 + (((kk * 4 + lk) ^ (row & 7)) * 8)];
      }
      #pragma unroll
      for (int nf = 0; nf < 2; ++nf) {
        int col = wn * 32 + nf * 16 + lr;
        int gi = col * 64 + (((kk * 4 + lk) ^ (col & 7)) * 8);
        bf16x8 bgf = *(const bf16x8*)&bg[gi];
        bf16x8 buf_ = *(const bf16x8*)&bu[gi];
        #pragma unroll
        for (int mf = 0; mf < 2; ++mf) {
          accg[mf][nf] = __builtin_amdgcn_mfma_f32_16x16x32_bf16(af[mf], bgf, accg[mf][nf], 0, 0, 0);
          accu[mf][nf] = __builtin_amdgcn_mfma_f32_16x16x32_bf16(af[mf], buf_, accu[mf][nf], 0, 0, 0);
        }
      }
    }
  };

  const int NST = HDIM / 64;  // 16
  STAGE(0, 0);
  STAGE(1, 1);
  WAIT4_BAR();
  for (int s = 0; s < NST; ++s) {
    int cur = s % 3;
    if (s + 2 < NST) {
      STAGE((s + 2) % 3, s + 2);
      COMPUTE(cur);
      WAIT4_BAR();
    } else if (s + 1 < NST) {
      COMPUTE(cur);
      WAIT0_BAR();
    } else {
      COMPUTE(cur);
    }
  }

  #pragma unroll
  for (int mf = 0; mf < 2; ++mf)
    #pragma unroll
    for (int nf = 0; nf < 2; ++nf)
      #pragma unroll
      for (int r = 0; r < 4; ++r) {
        int row = wm * 32 + mf * 16 + lk * 4 + r;
        int col = wn * 32 + nf * 16 + lr;
        float gv = accg[mf][nf][r], uv = accu[mf][nf][r];
        float h = gv / (1.f + expf(-gv)) * uv;
        mid[(size_t)(rowbase + row) * IC + ic0 + col] = __float2bfloat16(h);
      }
}

// ------- K3 tile: dout = mid @ Wd^T; 128m x 128n, 3-buf vmcnt(4) ------------
__device__ __forceinline__ void tile_down2(
    const __hip_bfloat16* __restrict__ mid, const __hip_bfloat16* __restrict__ wtd,
    int rowbase, int n0, int KD,
    __hip_bfloat16* __restrict__ dout, short* As, short* Bs) {
  int tid = threadIdx.x;
  int wave = tid >> 6, lane = tid & 63;
  int wm = wave >> 2, wn = wave & 3;
  int lr = lane & 15, lk = lane >> 4;

  int rh = lane >> 3;
  int lh = ((lane & 7) ^ rh) * 8;
  const short* ga0 = (const short*)mid + (size_t)(rowbase + wave * 16 + rh) * KD + lh;
  const short* ga1 = (const short*)mid + (size_t)(rowbase + wave * 16 + 8 + rh) * KD + lh;
  const short* gb0 = (const short*)wtd + (size_t)(n0 + wave * 16 + rh) * KD + lh;
  const short* gb1 = (const short*)wtd + (size_t)(n0 + wave * 16 + 8 + rh) * KD + lh;

  f32x4 acc[4][2];
  #pragma unroll
  for (int a = 0; a < 4; ++a)
    #pragma unroll
    for (int b = 0; b < 2; ++b) acc[a][b] = (f32x4)0.f;

  auto STAGE = [&](int buf, int s) {
    char* ab = (char*)As + buf * 16384 + wave * 2048;
    gld16(ga0 + s * 64, ab);
    gld16(ga1 + s * 64, ab + 1024);
    char* bb = (char*)Bs + buf * 16384 + wave * 2048;
    gld16(gb0 + s * 64, bb);
    gld16(gb1 + s * 64, bb + 1024);
  };
  auto COMPUTE = [&](int buf) {
    const short* as = As + buf * 8192;
    const short* bs = Bs + buf * 8192;
    #pragma unroll
    for (int kk = 0; kk < 2; ++kk) {
      bf16x8 af[4];
      #pragma unroll
      for (int mf = 0; mf < 4; ++mf) {
        int row = wm * 64 + mf * 16 + lr;
        af[mf] = *(const bf16x8*)&as[row * 64 + (((kk * 4 + lk) ^ (row & 7)) * 8)];
      }
      #pragma unroll
      for (int nf = 0; nf < 2; ++nf) {
        int col = wn * 32 + nf * 16 + lr;
        bf16x8 bf_ = *(const bf16x8*)&bs[col * 64 + (((kk * 4 + lk) ^ (col & 7)) * 8)];
        #pragma unroll
        for (int mf = 0; mf < 4; ++mf)
          acc[mf][nf] = __builtin_amdgcn_mfma_f32_16x16x32_bf16(af[mf], bf_, acc[mf][nf], 0, 0, 0);
      }
    }
  };

  const int NST = KD / 64;  // 8 or 16
  STAGE(0, 0);
  STAGE(1, 1);
  WAIT4_BAR();
  for (int s = 0; s < NST; ++s) {
    int cur = s % 3;
    if (s + 2 < NST) {
      STAGE((s + 2) % 3, s + 2);
      COMPUTE(cur);
      WAIT4_BAR();
    } else if (s + 1 < NST) {
      COMPUTE(cur);
      WAIT0_BAR();
    } else {
      COMPUTE(cur);
    }
  }

  #pragma unroll
  for (int mf = 0; mf < 4; ++mf)
    #pragma unroll
    for (int nf = 0; nf < 2; ++nf)
      #pragma unroll
      for (int r = 0; r < 4; ++r) {
        int row = wm * 64 + mf * 16 + lk * 4 + r;
        int col = wn * 32 + nf * 16 + lr;
        dout[(size_t)(rowbase + row) * HDIM + n0 + col] = __float2bfloat16(acc[mf][nf][r]);
      }
}

// ---------------- K2: routed + shared mid, 1 item/block ----------------
__global__ __launch_bounds__(512, 2) void k2_fused(
    const __hip_bfloat16* __restrict__ xb,
    const __hip_bfloat16* __restrict__ wt_g, const __hip_bfloat16* __restrict__ wt_u,
    const __hip_bfloat16* __restrict__ ts_g, const __hip_bfloat16* __restrict__ ts_u,
    const int* __restrict__ slot_tok, const int* __restrict__ tile_e,
    const int* __restrict__ tile_base, const int* __restrict__ nt_p,
    __hip_bfloat16* __restrict__ mid_r, __hip_bfloat16* __restrict__ mid_s) {
  __shared__ __align__(16) short As[3 * 8192];
  __shared__ __align__(16) short Bg[3 * 4096];
  __shared__ __align__(16) short Bu[3 * 4096];
  int q = gridDim.x >> 3;
  int item = (blockIdx.x & 7) * q + (blockIdx.x >> 3);
  int nrt = nt_p[0] * 8;
  int nitems = nrt + 128;
  if (item >= nitems) return;
  if (item < nrt) {
    int tile = item >> 3, c = item & 7;
    int e = tile_e[tile];
    tile_mid2(xb, wt_g + (size_t)e * IDIM * HDIM, wt_u + (size_t)e * IDIM * HDIM,
              slot_tok, tile_base[tile], c * 64, IDIM, mid_r, As, Bg, Bu);
  } else {
    int it = item - nrt;
    int mt = it >> 4, c = it & 15;
    tile_mid2(xb, ts_g, ts_u, nullptr, mt * 128, c * 64, SIDIM, mid_s, As, Bg, Bu);
  }
}

// ---------------- K3: routed + shared down, 1 item/block --------------------
__global__ __launch_bounds__(512, 2) void k3_fused(
    const __hip_bfloat16* __restrict__ mid_r, const __hip_bfloat16* __restrict__ mid_s,
    const __hip_bfloat16* __restrict__ wt_d, const __hip_bfloat16* __restrict__ ts_d,
    const int* __restrict__ tile_e, const int* __restrict__ tile_base,
    const int* __restrict__ nt_p,
    __hip_bfloat16* __restrict__ dout_r, __hip_bfloat16* __restrict__ dout_s) {
  __shared__ __align__(16) short As[3 * 8192];
  __shared__ __align__(16) short Bs[3 * 8192];
  int q = gridDim.x >> 3;
  int item = (blockIdx.x & 7) * q + (blockIdx.x >> 3);
  int nsh = 64;
  int nitems = nsh + nt_p[0] * 8;
  if (item >= nitems) return;
  if (item < nsh) {
    int mt = item >> 3, c = item & 7;
    tile_down2(mid_s, ts_d, mt * 128, c * 128, SIDIM, dout_s, As, Bs);
  } else {
    int it = item - nsh;
    int tile = it >> 3, c = it & 7;
    int e = tile_e[tile];
    tile_down2(mid_r, wt_d + (size_t)e * HDIM * IDIM, tile_base[tile], c * 128, IDIM,
               dout_r, As, Bs);
  }
}

// ---------------- K4: combine per token ----------------
__global__ __launch_bounds__(128) void k4_combine(
    const __hip_bfloat16* __restrict__ dout_r, const __hip_bfloat16* __restrict__ dout_s,
    const int* __restrict__ tslot, const float* __restrict__ wts,
    float* __restrict__ out) {
  int t = blockIdx.x;
  int tid = threadIdx.x;
  int sl[TOPKN]; float w[TOPKN];
  #pragma unroll
  for (int r = 0; r < TOPKN; ++r) {
    sl[r] = tslot[t * TOPKN + r];
    w[r] = wts[t * TOPKN + r] * 2.5f;
  }
  int h0 = tid * 8;
  float acc[8];
  bf16x8 vs = *(const bf16x8*)((const short*)dout_s + (size_t)t * HDIM + h0);
  #pragma unroll
  for (int j = 0; j < 8; ++j) acc[j] = bf2f(vs[j]);
  #pragma unroll
  for (int r = 0; r < TOPKN; ++r) {
    bf16x8 v = *(const bf16x8*)((const short*)dout_r + (size_t)sl[r] * HDIM + h0);
    #pragma unroll
    for (int j = 0; j < 8; ++j) acc[j] += w[r] * bf2f(v[j]);
  }
  float* op = out + (size_t)t * HDIM + h0;
  *(float4*)op = make_float4(acc[0], acc[1], acc[2], acc[3]);
  *(float4*)(op + 4) = make_float4(acc[4], acc[5], acc[6], acc[7]);
}

// ---------------- launch ----------------
extern "C" void kernel_launch(void* const* d_in, const int* in_sizes, int n_in,
                              void* d_out, int out_size, void* d_ws, size_t ws_size,
                              hipStream_t stream) {
  (void)in_sizes; (void)n_in; (void)out_size; (void)ws_size;
  const float* x      = (const float*)d_in[0];
  const float* gate_w = (const float*)d_in[1];
  const float* ebias  = (const float*)d_in[2];
  const float* wgate  = (const float*)d_in[3];
  const float* wup    = (const float*)d_in[4];
  const float* wdown  = (const float*)d_in[5];
  const float* swg    = (const float*)d_in[6];
  const float* swu    = (const float*)d_in[7];
  const float* swd    = (const float*)d_in[8];
  float* out = (float*)d_out;

  char* ws = (char*)d_ws;
  int*   counts    = (int*)(ws + 0);
  int*   cursor    = (int*)(ws + 256);
  int*   eoff      = (int*)(ws + 512);
  int*   nt_p      = (int*)(ws + 1024);
  int*   tile_e    = (int*)(ws + 1088);
  int*   tile_base = (int*)(ws + 2112);
  int*   ids       = (int*)(ws + 4096);
  float* wts       = (float*)(ws + 28672);
  int*   tslot     = (int*)(ws + 53248);
  int*   slot_tok  = (int*)(ws + 77824);
  __hip_bfloat16* xb   = (__hip_bfloat16*)(ws + 262144);
  __hip_bfloat16* wt_g = (__hip_bfloat16*)(ws + 4194304);
  __hip_bfloat16* wt_u = (__hip_bfloat16*)(ws + 71303168);
  __hip_bfloat16* ts_g = (__hip_bfloat16*)(ws + 138412032);
  __hip_bfloat16* ts_u = (__hip_bfloat16*)(ws + 140509184);
  __hip_bfloat16* wt_d = (__hip_bfloat16*)(ws + 4194304);
  __hip_bfloat16* ts_d = (__hip_bfloat16*)(ws + 71303168);
  __hip_bfloat16* dout_r = (__hip_bfloat16*)(ws + 73400320);
  __hip_bfloat16* dout_s = (__hip_bfloat16*)(ws + 102760448);
  __hip_bfloat16* mid_r = (__hip_bfloat16*)(ws + 142606336);
  __hip_bfloat16* mid_s = (__hip_bfloat16*)(ws + 157286400);

  k0_init<<<1, 128, 0, stream>>>(counts, cursor);
  k1_gate<<<T_TOK, 256, 0, stream>>>(x, gate_w, ebias, ids, wts, counts);
  k1b_scan<<<1, 256, 0, stream>>>(counts, eoff, tile_e, tile_base, nt_p, slot_tok);
  k1c_fill<<<(T_TOK * TOPKN + 255) / 256, 256, 0, stream>>>(ids, eoff, cursor, slot_tok, tslot);
  prep1<<<1120, 256, 0, stream>>>(wgate, wup, swg, swu, x, wt_g, wt_u, ts_g, ts_u, xb);
  k2_fused<<<1024, 512, 0, stream>>>(xb, wt_g, wt_u, ts_g, ts_u, slot_tok,
                                     tile_e, tile_base, nt_p, mid_r, mid_s);
  prep2<<<1040, 256, 0, stream>>>(wdown, swd, wt_d, ts_d);
  k3_fused<<<960, 512, 0, stream>>>(mid_r, mid_s, wt_d, ts_d, tile_e, tile_base,
                                    nt_p, dout_r, dout_s);
  k4_combine<<<T_TOK, 128, 0, stream>>>(dout_r, dout_s, tslot, wts, out);
}

// Round 11
// 323.340 us; speedup vs baseline: 1.0743x; 1.0743x over previous
//
#include <hip/hip_runtime.h>
#include <hip/hip_bf16.h>

#define T_TOK 1024
#define HDIM  1024
#define NEXP  64
#define IDIM  512
#define SIDIM 1024
#define NGRP  8
#define GSZ   8
#define TKGN  3
#define TOPKN 6
#define CAPS  14336

typedef __attribute__((ext_vector_type(8))) short bf16x8;
typedef __attribute__((ext_vector_type(4))) float f32x4;

__device__ __forceinline__ short f2bf(float f) {
  union { __hip_bfloat16 h; short s; } u;
  u.h = __float2bfloat16(f);
  return u.s;
}
__device__ __forceinline__ float bf2f(short s) {
  union { float f; unsigned u; } c;
  c.u = ((unsigned)(unsigned short)s) << 16;
  return c.f;
}

// global->LDS direct copy, 16B per lane. LDS dest = wave-uniform base + lane*16.
__device__ __forceinline__ void gld16(const void* g, void* l) {
  typedef __attribute__((address_space(1))) const unsigned int GU;
  typedef __attribute__((address_space(3))) unsigned int LU;
  __builtin_amdgcn_global_load_lds((GU*)g, (LU*)l, 16, 0, 0);
}

// counted-vmcnt barrier: with 6 gld16/wave/stage, retiring to 6 leaves the
// newest stage in flight while the previous stage is guaranteed complete.
#define WAIT6_BAR() asm volatile("s_waitcnt vmcnt(6) lgkmcnt(0)\n\ts_barrier" ::: "memory")
#define WAIT0_BAR() asm volatile("s_waitcnt vmcnt(0) lgkmcnt(0)\n\ts_barrier" ::: "memory")

// ---------------- K0: zero counters ----------------
__global__ void k0_init(int* counts, int* cursor) {
  int i = threadIdx.x;
  if (i < NEXP) { counts[i] = 0; cursor[i] = 0; }
}

// ---------------- kX: x fp32 -> bf16 ----------------
__global__ __launch_bounds__(128) void kx_conv(const float* __restrict__ x,
                                               __hip_bfloat16* __restrict__ xb) {
  int row = blockIdx.x;
  int c = threadIdx.x * 8;
  const float* s = x + (size_t)row * HDIM + c;
  float4 v0 = *(const float4*)s;
  float4 v1 = *(const float4*)(s + 4);
  bf16x8 o;
  o[0] = f2bf(v0.x); o[1] = f2bf(v0.y); o[2] = f2bf(v0.z); o[3] = f2bf(v0.w);
  o[4] = f2bf(v1.x); o[5] = f2bf(v1.y); o[6] = f2bf(v1.z); o[7] = f2bf(v1.w);
  *(bf16x8*)((short*)xb + (size_t)row * HDIM + c) = o;
}

// ---------------- K1: gating + grouped top-k (1 token / block) --------------
__global__ __launch_bounds__(256) void k1_gate(
    const float* __restrict__ x, const float* __restrict__ gw,
    const float* __restrict__ ebias,
    int* __restrict__ ids, float* __restrict__ wts, int* __restrict__ counts) {
  int t = blockIdx.x;
  int tid = threadIdx.x;
  int lane = tid & 63;   // expert
  int sub = tid >> 6;    // h-chunk
  __shared__ float sx[HDIM];
  __shared__ double spart[4][NEXP];
  __shared__ float s_sc[NEXP], s_sig[NEXP];
  *(float4*)&sx[tid * 4] = *(const float4*)(x + (size_t)t * HDIM + tid * 4);
  __syncthreads();
  const float* gwp = gw + lane;
  int h0 = sub * 256;
  double a0 = 0.0, a1 = 0.0, a2 = 0.0, a3 = 0.0;
  for (int h = h0; h < h0 + 256; h += 4) {
    a0 += (double)sx[h + 0] * (double)gwp[(size_t)(h + 0) * NEXP];
    a1 += (double)sx[h + 1] * (double)gwp[(size_t)(h + 1) * NEXP];
    a2 += (double)sx[h + 2] * (double)gwp[(size_t)(h + 2) * NEXP];
    a3 += (double)sx[h + 3] * (double)gwp[(size_t)(h + 3) * NEXP];
  }
  spart[sub][lane] = (a0 + a1) + (a2 + a3);
  __syncthreads();
  if (tid < NEXP) {
    float logit = (float)(((spart[0][tid] + spart[1][tid]) +
                           (spart[2][tid] + spart[3][tid])));
    float sig = 1.f / (1.f + expf(-logit));
    s_sig[tid] = sig;
    s_sc[tid] = sig + ebias[tid];
  }
  __syncthreads();
  if (tid == 0) {
    const float* ssc = s_sc;
    const float* ssig = s_sig;
    float gsum[NGRP];
    for (int g = 0; g < NGRP; ++g) {
      float m1 = -1e30f; int i1 = -1;
      for (int i = 0; i < GSZ; ++i) {
        float v = ssc[g * GSZ + i];
        if (v > m1) { m1 = v; i1 = i; }
      }
      float m2 = -1e30f;
      for (int i = 0; i < GSZ; ++i) {
        if (i == i1) continue;
        float v = ssc[g * GSZ + i];
        if (v > m2) m2 = v;
      }
      gsum[g] = m1 + m2;
    }
    unsigned gselmask = 0;
    for (int r = 0; r < TKGN; ++r) {
      float best = -1e30f; int bi = 0;
      for (int g = 0; g < NGRP; ++g) {
        if ((gselmask >> g) & 1) continue;
        if (gsum[g] > best) { best = gsum[g]; bi = g; }
      }
      gselmask |= 1u << bi;
    }
    unsigned long long taken = 0;
    int chosen[TOPKN]; float wsum = 0.f;
    for (int r = 0; r < TOPKN; ++r) {
      float best = -1e30f; int bi = 0;
      for (int e = 0; e < NEXP; ++e) {
        if (!((gselmask >> (e >> 3)) & 1)) continue;
        if ((taken >> e) & 1) continue;
        float v = ssc[e];
        if (v > best) { best = v; bi = e; }
      }
      taken |= 1ull << bi;
      chosen[r] = bi;
      wsum += ssig[bi];
    }
    for (int r = 0; r < TOPKN; ++r) {
      ids[t * TOPKN + r] = chosen[r];
      wts[t * TOPKN + r] = ssig[chosen[r]] / wsum;
      atomicAdd(&counts[chosen[r]], 1);
    }
  }
}

// ---------------- K1b: offsets + worklist + slot init ----------------
__global__ void k1b_scan(const int* __restrict__ counts, int* __restrict__ eoff,
                         int* __restrict__ tile_e, int* __restrict__ tile_base,
                         int* __restrict__ nt_p, int* __restrict__ slot_tok) {
  __shared__ int soff[NEXP + 1];
  __shared__ int s_total;
  int tid = threadIdx.x;
  if (tid == 0) {
    int o = 0, idx = 0;
    for (int e = 0; e < NEXP; ++e) {
      soff[e] = o;
      int ntile = (counts[e] + 127) >> 7;
      for (int t2 = 0; t2 < ntile; ++t2) { tile_e[idx] = e; tile_base[idx] = o + t2 * 128; ++idx; }
      o += ntile << 7;
    }
    soff[NEXP] = o; nt_p[0] = idx; s_total = o;
  }
  __syncthreads();
  if (tid <= NEXP) eoff[tid] = soff[tid];
  int total = s_total;
  for (int i = tid; i < total; i += blockDim.x) slot_tok[i] = 0;
}

// ---------------- K1c: fill compact slots + token->slot map ----------------
__global__ void k1c_fill(const int* __restrict__ ids,
                         const int* __restrict__ eoff, int* __restrict__ cursor,
                         int* __restrict__ slot_tok, int* __restrict__ tslot) {
  int i = blockIdx.x * blockDim.x + threadIdx.x;
  if (i >= T_TOK * TOPKN) return;
  int e = ids[i];
  int s = eoff[e] + atomicAdd(&cursor[e], 1);
  slot_tok[s] = i / TOPKN;
  tslot[i] = s;
}

// ------- K2 tile: mid = silu(A@Wg^T)*(A@Wu^T); fp32 B direct, 3-buf vmcnt(6)
// A: bf16 xb rows (pre-swizzled granules, gld16). B: fp32 W[h][i] rows staged
// LINEAR (coalesced gld16); transpose happens at LDS-read (col reads + cvt).
__device__ __forceinline__ void tile_mid2(
    const __hip_bfloat16* __restrict__ xb,
    const float* __restrict__ wg, const float* __restrict__ wu,
    const int* __restrict__ slot_tok, int rowbase, int ic0, int IC,
    __hip_bfloat16* __restrict__ mid,
    short* As, float* Bg, float* Bu) {
  int tid = threadIdx.x;
  int wave = tid >> 6, lane = tid & 63;
  int wm = wave >> 1, wn = wave & 1;
  int lr = lane & 15, lk = lane >> 4;

  // A staging (proven R7 path): pre-swizzled source granules, linear LDS
  int rh = lane >> 3;
  int lh = ((lane & 7) ^ rh) * 8;
  int r0 = rowbase + wave * 16 + rh;
  int t0 = slot_tok ? slot_tok[r0] : r0;
  int t1 = slot_tok ? slot_tok[r0 + 8] : (r0 + 8);
  const short* ga0 = (const short*)xb + (size_t)t0 * HDIM + lh;
  const short* ga1 = (const short*)xb + (size_t)t1 * HDIM + lh;
  // B staging: rows k (=h), 64 fp32 cols; per gld16 issue = 4 rows
  int brow = wave * 8 + (lane >> 4);
  const float* gbg = wg + (size_t)brow * IC + ic0 + (lane & 15) * 4;
  const float* gbu = wu + (size_t)brow * IC + ic0 + (lane & 15) * 4;

  f32x4 accg[2][2], accu[2][2];
  #pragma unroll
  for (int a = 0; a < 2; ++a)
    #pragma unroll
    for (int b = 0; b < 2; ++b) { accg[a][b] = (f32x4)0.f; accu[a][b] = (f32x4)0.f; }

  auto STAGE = [&](int buf, int s) {
    char* ab = (char*)As + buf * 16384 + wave * 2048;
    gld16(ga0 + s * 64, ab);
    gld16(ga1 + s * 64, ab + 1024);
    char* bgb = (char*)Bg + buf * 16384 + wave * 2048;
    gld16(gbg + (size_t)s * 64 * IC, bgb);
    gld16(gbg + (size_t)(s * 64 + 4) * IC, bgb + 1024);
    char* bub = (char*)Bu + buf * 16384 + wave * 2048;
    gld16(gbu + (size_t)s * 64 * IC, bub);
    gld16(gbu + (size_t)(s * 64 + 4) * IC, bub + 1024);
  };
  auto COMPUTE = [&](int buf) {
    const short* as = As + buf * 8192;
    const float* bg = Bg + buf * 4096;
    const float* bu = Bu + buf * 4096;
    #pragma unroll
    for (int kk = 0; kk < 2; ++kk) {
      bf16x8 af[2];
      #pragma unroll
      for (int mf = 0; mf < 2; ++mf) {
        int row = wm * 32 + mf * 16 + lr;
        af[mf] = *(const bf16x8*)&as[row * 64 + (((kk * 4 + lk) ^ (row & 7)) * 8)];
      }
      #pragma unroll
      for (int nf = 0; nf < 2; ++nf) {
        int col = wn * 32 + nf * 16 + lr;
        const float* pg = bg + (kk * 32 + lk * 8) * 64 + col;
        const float* pu = bu + (kk * 32 + lk * 8) * 64 + col;
        bf16x8 bgf, buf_;
        #pragma unroll
        for (int j = 0; j < 8; ++j) {
          bgf[j] = f2bf(pg[j * 64]);
          buf_[j] = f2bf(pu[j * 64]);
        }
        #pragma unroll
        for (int mf = 0; mf < 2; ++mf) {
          accg[mf][nf] = __builtin_amdgcn_mfma_f32_16x16x32_bf16(af[mf], bgf, accg[mf][nf], 0, 0, 0);
          accu[mf][nf] = __builtin_amdgcn_mfma_f32_16x16x32_bf16(af[mf], buf_, accu[mf][nf], 0, 0, 0);
        }
      }
    }
  };

  const int NST = HDIM / 64;  // 16
  STAGE(0, 0);
  STAGE(1, 1);
  WAIT6_BAR();
  for (int s = 0; s < NST; ++s) {
    int cur = s % 3;
    if (s + 2 < NST) {
      STAGE((s + 2) % 3, s + 2);
      COMPUTE(cur);
      WAIT6_BAR();
    } else if (s + 1 < NST) {
      COMPUTE(cur);
      WAIT0_BAR();
    } else {
      COMPUTE(cur);
    }
  }

  #pragma unroll
  for (int mf = 0; mf < 2; ++mf)
    #pragma unroll
    for (int nf = 0; nf < 2; ++nf)
      #pragma unroll
      for (int r = 0; r < 4; ++r) {
        int row = wm * 32 + mf * 16 + lk * 4 + r;
        int col = wn * 32 + nf * 16 + lr;
        float gv = accg[mf][nf][r], uv = accu[mf][nf][r];
        float h = gv / (1.f + expf(-gv)) * uv;
        mid[(size_t)(rowbase + row) * IC + ic0 + col] = __float2bfloat16(h);
      }
}

// ------- K3 tile: dout = mid @ Wd^T; 128m x 128n, fp32 B direct, vmcnt(6) ---
__device__ __forceinline__ void tile_down2(
    const __hip_bfloat16* __restrict__ mid, const float* __restrict__ wd,
    int rowbase, int n0, int KD,
    __hip_bfloat16* __restrict__ dout, short* As, float* Bs) {
  int tid = threadIdx.x;
  int wave = tid >> 6, lane = tid & 63;
  int wm = wave >> 2, wn = wave & 3;
  int lr = lane & 15, lk = lane >> 4;

  int rh = lane >> 3;
  int lh = ((lane & 7) ^ rh) * 8;
  const short* ga0 = (const short*)mid + (size_t)(rowbase + wave * 16 + rh) * KD + lh;
  const short* ga1 = (const short*)mid + (size_t)(rowbase + wave * 16 + 8 + rh) * KD + lh;
  // B: rows k (=i), 128 fp32 cols (=h); per gld16 issue = 2 rows
  int brow = wave * 8 + (lane >> 5);
  const float* gb = wd + (size_t)brow * HDIM + n0 + (lane & 31) * 4;

  f32x4 acc[4][2];
  #pragma unroll
  for (int a = 0; a < 4; ++a)
    #pragma unroll
    for (int b = 0; b < 2; ++b) acc[a][b] = (f32x4)0.f;

  auto STAGE = [&](int buf, int s) {
    char* ab = (char*)As + buf * 16384 + wave * 2048;
    gld16(ga0 + s * 64, ab);
    gld16(ga1 + s * 64, ab + 1024);
    char* bb = (char*)Bs + buf * 32768 + wave * 4096;
    gld16(gb + (size_t)s * 64 * HDIM, bb);
    gld16(gb + (size_t)(s * 64 + 2) * HDIM, bb + 1024);
    gld16(gb + (size_t)(s * 64 + 4) * HDIM, bb + 2048);
    gld16(gb + (size_t)(s * 64 + 6) * HDIM, bb + 3072);
  };
  auto COMPUTE = [&](int buf) {
    const short* as = As + buf * 8192;
    const float* bs = Bs + buf * 8192;
    #pragma unroll
    for (int kk = 0; kk < 2; ++kk) {
      bf16x8 af[4];
      #pragma unroll
      for (int mf = 0; mf < 4; ++mf) {
        int row = wm * 64 + mf * 16 + lr;
        af[mf] = *(const bf16x8*)&as[row * 64 + (((kk * 4 + lk) ^ (row & 7)) * 8)];
      }
      #pragma unroll
      for (int nf = 0; nf < 2; ++nf) {
        int col = wn * 32 + nf * 16 + lr;
        const float* pb = bs + (kk * 32 + lk * 8) * 128 + col;
        bf16x8 bf_;
        #pragma unroll
        for (int j = 0; j < 8; ++j) bf_[j] = f2bf(pb[j * 128]);
        #pragma unroll
        for (int mf = 0; mf < 4; ++mf)
          acc[mf][nf] = __builtin_amdgcn_mfma_f32_16x16x32_bf16(af[mf], bf_, acc[mf][nf], 0, 0, 0);
      }
    }
  };

  const int NST = KD / 64;  // 8 or 16
  STAGE(0, 0);
  STAGE(1, 1);
  WAIT6_BAR();
  for (int s = 0; s < NST; ++s) {
    int cur = s % 3;
    if (s + 2 < NST) {
      STAGE((s + 2) % 3, s + 2);
      COMPUTE(cur);
      WAIT6_BAR();
    } else if (s + 1 < NST) {
      COMPUTE(cur);
      WAIT0_BAR();
    } else {
      COMPUTE(cur);
    }
  }

  #pragma unroll
  for (int mf = 0; mf < 4; ++mf)
    #pragma unroll
    for (int nf = 0; nf < 2; ++nf)
      #pragma unroll
      for (int r = 0; r < 4; ++r) {
        int row = wm * 64 + mf * 16 + lk * 4 + r;
        int col = wn * 32 + nf * 16 + lr;
        dout[(size_t)(rowbase + row) * HDIM + n0 + col] = __float2bfloat16(acc[mf][nf][r]);
      }
}

// ---------------- K2: routed + shared mid, 1 item/block ----------------
__global__ __launch_bounds__(512) void k2_fused(
    const __hip_bfloat16* __restrict__ xb,
    const float* __restrict__ Wg, const float* __restrict__ Wu,
    const float* __restrict__ swg, const float* __restrict__ swu,
    const int* __restrict__ slot_tok, const int* __restrict__ tile_e,
    const int* __restrict__ tile_base, const int* __restrict__ nt_p,
    __hip_bfloat16* __restrict__ mid_r, __hip_bfloat16* __restrict__ mid_s) {
  __shared__ __align__(16) short As[3 * 8192];   // 48 KB
  __shared__ __align__(16) float Bg[3 * 4096];   // 48 KB
  __shared__ __align__(16) float Bu[3 * 4096];   // 48 KB
  int q = gridDim.x >> 3;
  int item = (blockIdx.x & 7) * q + (blockIdx.x >> 3);
  int nrt = nt_p[0] * 8;
  int nitems = nrt + 128;
  if (item >= nitems) return;
  if (item < nrt) {
    int tile = item >> 3, c = item & 7;
    int e = tile_e[tile];
    tile_mid2(xb, Wg + (size_t)e * HDIM * IDIM, Wu + (size_t)e * HDIM * IDIM,
              slot_tok, tile_base[tile], c * 64, IDIM, mid_r, As, Bg, Bu);
  } else {
    int it = item - nrt;
    int mt = it >> 4, c = it & 15;
    tile_mid2(xb, swg, swu, nullptr, mt * 128, c * 64, SIDIM, mid_s, As, Bg, Bu);
  }
}

// ---------------- K3: routed + shared down, 1 item/block --------------------
__global__ __launch_bounds__(512) void k3_fused(
    const __hip_bfloat16* __restrict__ mid_r, const __hip_bfloat16* __restrict__ mid_s,
    const float* __restrict__ Wd, const float* __restrict__ swd,
    const int* __restrict__ tile_e, const int* __restrict__ tile_base,
    const int* __restrict__ nt_p,
    __hip_bfloat16* __restrict__ dout_r, __hip_bfloat16* __restrict__ dout_s) {
  __shared__ __align__(16) short As[3 * 8192];   // 48 KB
  __shared__ __align__(16) float Bs[3 * 8192];   // 96 KB
  int q = gridDim.x >> 3;
  int item = (blockIdx.x & 7) * q + (blockIdx.x >> 3);
  int nsh = 64;
  int nitems = nsh + nt_p[0] * 8;
  if (item >= nitems) return;
  if (item < nsh) {
    int mt = item >> 3, c = item & 7;
    tile_down2(mid_s, swd, mt * 128, c * 128, SIDIM, dout_s, As, Bs);
  } else {
    int it = item - nsh;
    int tile = it >> 3, c = it & 7;
    int e = tile_e[tile];
    tile_down2(mid_r, Wd + (size_t)e * IDIM * HDIM, tile_base[tile], c * 128, IDIM,
               dout_r, As, Bs);
  }
}

// ---------------- K4: combine per token ----------------
__global__ __launch_bounds__(128) void k4_combine(
    const __hip_bfloat16* __restrict__ dout_r, const __hip_bfloat16* __restrict__ dout_s,
    const int* __restrict__ tslot, const float* __restrict__ wts,
    float* __restrict__ out) {
  int t = blockIdx.x;
  int tid = threadIdx.x;
  int sl[TOPKN]; float w[TOPKN];
  #pragma unroll
  for (int r = 0; r < TOPKN; ++r) {
    sl[r] = tslot[t * TOPKN + r];
    w[r] = wts[t * TOPKN + r] * 2.5f;
  }
  int h0 = tid * 8;
  float acc[8];
  bf16x8 vs = *(const bf16x8*)((const short*)dout_s + (size_t)t * HDIM + h0);
  #pragma unroll
  for (int j = 0; j < 8; ++j) acc[j] = bf2f(vs[j]);
  #pragma unroll
  for (int r = 0; r < TOPKN; ++r) {
    bf16x8 v = *(const bf16x8*)((const short*)dout_r + (size_t)sl[r] * HDIM + h0);
    #pragma unroll
    for (int j = 0; j < 8; ++j) acc[j] += w[r] * bf2f(v[j]);
  }
  float* op = out + (size_t)t * HDIM + h0;
  *(float4*)op = make_float4(acc[0], acc[1], acc[2], acc[3]);
  *(float4*)(op + 4) = make_float4(acc[4], acc[5], acc[6], acc[7]);
}

// ---------------- launch ----------------
extern "C" void kernel_launch(void* const* d_in, const int* in_sizes, int n_in,
                              void* d_out, int out_size, void* d_ws, size_t ws_size,
                              hipStream_t stream) {
  (void)in_sizes; (void)n_in; (void)out_size; (void)ws_size;
  const float* x      = (const float*)d_in[0];
  const float* gate_w = (const float*)d_in[1];
  const float* ebias  = (const float*)d_in[2];
  const float* wgate  = (const float*)d_in[3];
  const float* wup    = (const float*)d_in[4];
  const float* wdown  = (const float*)d_in[5];
  const float* swg    = (const float*)d_in[6];
  const float* swu    = (const float*)d_in[7];
  const float* swd    = (const float*)d_in[8];
  float* out = (float*)d_out;

  char* ws = (char*)d_ws;
  int*   counts    = (int*)(ws + 0);
  int*   cursor    = (int*)(ws + 256);
  int*   eoff      = (int*)(ws + 512);
  int*   nt_p      = (int*)(ws + 1024);
  int*   tile_e    = (int*)(ws + 1088);
  int*   tile_base = (int*)(ws + 2112);
  int*   ids       = (int*)(ws + 4096);
  float* wts       = (float*)(ws + 28672);
  int*   tslot     = (int*)(ws + 53248);
  int*   slot_tok  = (int*)(ws + 77824);
  __hip_bfloat16* xb     = (__hip_bfloat16*)(ws + 262144);
  __hip_bfloat16* dout_r = (__hip_bfloat16*)(ws + 73400320);
  __hip_bfloat16* dout_s = (__hip_bfloat16*)(ws + 102760448);
  __hip_bfloat16* mid_r  = (__hip_bfloat16*)(ws + 142606336);
  __hip_bfloat16* mid_s  = (__hip_bfloat16*)(ws + 157286400);

  k0_init<<<1, 128, 0, stream>>>(counts, cursor);
  k1_gate<<<T_TOK, 256, 0, stream>>>(x, gate_w, ebias, ids, wts, counts);
  k1b_scan<<<1, 256, 0, stream>>>(counts, eoff, tile_e, tile_base, nt_p, slot_tok);
  k1c_fill<<<(T_TOK * TOPKN + 255) / 256, 256, 0, stream>>>(ids, eoff, cursor, slot_tok, tslot);
  kx_conv<<<T_TOK, 128, 0, stream>>>(x, xb);
  // k2: max items = 112*8 + 128 = 1024
  k2_fused<<<1024, 512, 0, stream>>>(xb, wgate, wup, swg, swu, slot_tok,
                                     tile_e, tile_base, nt_p, mid_r, mid_s);
  // k3: max items = 64 + 112*8 = 960
  k3_fused<<<960, 512, 0, stream>>>(mid_r, mid_s, wdown, swd, tile_e, tile_base,
                                    nt_p, dout_r, dout_s);
  k4_combine<<<T_TOK, 128, 0, stream>>>(dout_r, dout_s, tslot, wts, out);
}